// Round 12
// baseline (450.669 us; speedup 1.0000x reference)
//
#include <hip/hip_runtime.h>

#define E_ 8
#define C_ 1024
#define H_ 2048
#define B_ 8
#define T_ 1024
#define NGRP 64          // B_*E_
#define NROWS 16384      // B_*T_*K

typedef __bf16 bf16x8 __attribute__((ext_vector_type(8)));
typedef float f32x4 __attribute__((ext_vector_type(4)));
typedef unsigned short u16;
typedef u16 u16x8 __attribute__((ext_vector_type(8)));

__device__ __forceinline__ u16 f2bf(float f) {
  unsigned u = __float_as_uint(f);
  u += 0x7FFFu + ((u >> 16) & 1u);   // RNE; inputs finite
  return (u16)(u >> 16);
}

// async global->LDS, 16B per lane; lds dst is wave-uniform base + lane*16
__device__ __forceinline__ void gl16(const u16* g, u16* l) {
  __builtin_amdgcn_global_load_lds(
      (const __attribute__((address_space(1))) void*)g,
      (__attribute__((address_space(3))) void*)l, 16, 0, 0);
}

#define MFMA __builtin_amdgcn_mfma_f32_16x16x32_bf16
#define BAR() __builtin_amdgcn_s_barrier()
#define VMCNT(N) asm volatile("s_waitcnt vmcnt(" #N ")" ::: "memory")
#define PRIO1() __builtin_amdgcn_s_setprio(1)
#define PRIO0() __builtin_amdgcn_s_setprio(0)

// ---------- weights: in [E][R][S] f32 -> out [E][S][R] bf16 (transpose) ----------
// 16B global writes (ushort8); 64x64 tile; pad 68 keeps write-gather <=2-way.
__global__ __launch_bounds__(256) void k_wt(const float* __restrict__ in,
                                            u16* __restrict__ out, int R, int S) {
  __shared__ u16 tile[64][68];
  int e = blockIdx.z;
  int s0 = blockIdx.x * 64, r0 = blockIdx.y * 64;
  int tx = threadIdx.x & 15, ty = threadIdx.x >> 4;
  const float* src = in + ((size_t)e * R + r0) * S + s0;
  #pragma unroll
  for (int i = 0; i < 4; ++i) {
    int rr = i * 16 + ty;
    float4 v = *reinterpret_cast<const float4*>(src + (size_t)rr * S + tx * 4);
    tile[rr][tx * 4 + 0] = f2bf(v.x);
    tile[rr][tx * 4 + 1] = f2bf(v.y);
    tile[rr][tx * 4 + 2] = f2bf(v.z);
    tile[rr][tx * 4 + 3] = f2bf(v.w);
  }
  __syncthreads();
  int tx2 = threadIdx.x & 7, sy = threadIdx.x >> 3;   // 8 x 32
  u16* dst = out + ((size_t)e * S + s0) * R + r0;
  #pragma unroll
  for (int i = 0; i < 2; ++i) {
    int ss = i * 32 + sy;
    u16x8 o;
    #pragma unroll
    for (int k = 0; k < 8; ++k) o[k] = tile[tx2 * 8 + k][ss];
    *reinterpret_cast<u16x8*>(dst + (size_t)ss * R + tx2 * 8) = o;
  }
}

// ---------- router pass 1: wave per token; float4 x-read, ushort4 xb-write ----------
__global__ __launch_bounds__(256) void k_router(const float* __restrict__ x,
                                                const float* __restrict__ rw,
                                                u16* __restrict__ xb,
                                                int* __restrict__ sel_e,
                                                float* __restrict__ sel_p) {
  int lane = threadIdx.x & 63;
  int tt = blockIdx.x * 4 + (threadIdx.x >> 6);    // token id 0..8191
  const float* xr = x + (size_t)tt * C_;
  u16* xo = xb + (size_t)tt * C_;
  float acc[8] = {0, 0, 0, 0, 0, 0, 0, 0};
  #pragma unroll
  for (int j = 0; j < 4; ++j) {
    int c0 = j * 256 + lane * 4;
    float4 xv = *reinterpret_cast<const float4*>(xr + c0);
    ushort4 o;
    o.x = f2bf(xv.x); o.y = f2bf(xv.y); o.z = f2bf(xv.z); o.w = f2bf(xv.w);
    *reinterpret_cast<ushort4*>(xo + c0) = o;
    float xs[4] = {xv.x, xv.y, xv.z, xv.w};
    #pragma unroll
    for (int u = 0; u < 4; ++u) {
      int c = c0 + u;
      float4 r0 = reinterpret_cast<const float4*>(rw + c * 8)[0];
      float4 r1 = reinterpret_cast<const float4*>(rw + c * 8)[1];
      float xv1 = xs[u];
      acc[0] += xv1 * r0.x; acc[1] += xv1 * r0.y; acc[2] += xv1 * r0.z; acc[3] += xv1 * r0.w;
      acc[4] += xv1 * r1.x; acc[5] += xv1 * r1.y; acc[6] += xv1 * r1.z; acc[7] += xv1 * r1.w;
    }
  }
  #pragma unroll
  for (int e = 0; e < 8; ++e)
    #pragma unroll
    for (int off = 32; off; off >>= 1)
      acc[e] += __shfl_xor(acc[e], off);
  if (lane == 0) {
    int e0 = 0;
    #pragma unroll
    for (int e = 1; e < 8; ++e) if (acc[e] > acc[e0]) e0 = e;   // ties -> lower idx
    int e1 = -1;
    #pragma unroll
    for (int e = 0; e < 8; ++e)
      if (e != e0 && (e1 < 0 || acc[e] > acc[e1])) e1 = e;
    float l0 = acc[e0], l1 = acc[e1];
    sel_e[tt * 2 + 0] = e0;
    sel_e[tt * 2 + 1] = e1;
    sel_p[tt * 2 + 0] = 1.f / (1.f + expf(l1 - l0));
    sel_p[tt * 2 + 1] = 1.f / (1.f + expf(l0 - l1));
  }
}

// ---------- router pass 2: per-batch placement via LDS atomics ----------
__global__ __launch_bounds__(256) void k_place(const int* __restrict__ sel_e,
                                               const float* __restrict__ sel_p,
                                               int* __restrict__ counts,
                                               int* __restrict__ tok,
                                               float* __restrict__ pw,
                                               int* __restrict__ inv) {
  __shared__ int cnt[8];
  int b = blockIdx.x;
  if (threadIdx.x < 8) cnt[threadIdx.x] = 0;
  __syncthreads();
  for (int i = 0; i < 4; ++i) {
    int t = i * 256 + threadIdx.x;
    int tt = b * T_ + t;
    #pragma unroll
    for (int k = 0; k < 2; ++k) {
      int e = sel_e[tt * 2 + k];
      float p = sel_p[tt * 2 + k];
      int slot = atomicAdd(&cnt[e], 1);        // LDS atomic: fast, block-local
      int g = b * 8 + e;
      tok[g * T_ + slot] = t;
      pw[g * T_ + slot] = p;
      inv[tt * 2 + k] = g * T_ + slot;
    }
  }
  __syncthreads();
  if (threadIdx.x < 8) counts[b * 8 + threadIdx.x] = cnt[threadIdx.x];
}

// ---------- exclusive prefix over 64 counts ----------
__global__ void k_prefix(const int* __restrict__ counts, int* __restrict__ offsets) {
  if (threadIdx.x == 0) {
    int s = 0;
    for (int i = 0; i < NGRP; ++i) { offsets[i] = s; s += counts[i]; }
    offsets[NGRP] = s;
  }
}

// ---------- GEMM1: inter = (Xe@Wfc+bfc) * silu(Xe@Wg+bg), bf16 out ----------
// r7 kernel VERBATIM (session-best 234us). kk-split units, 4 phases/tile,
// counted vmcnt 6/5/6/5, setprio; known benign ~1.4e7 bank conflicts.
__global__ __launch_bounds__(512) void k_ffn1(
    const u16* __restrict__ xb, const u16* __restrict__ wfcT, const u16* __restrict__ wgT,
    const float* __restrict__ bfc, const float* __restrict__ bg,
    const int* __restrict__ counts, const int* __restrict__ offsets,
    const int* __restrict__ tok, u16* __restrict__ inter) {
  int bid = blockIdx.x;
  int e = bid & 7;                  // XCD pin
  int r = bid >> 3;                 // [0,512)
  int chunk = r >> 7;               // [0,4)  4-coltile chunk (2MB weights -> L2)
  int rr = r & 127;
  int brt = rr >> 2;                // [0,32) (b, rowtile); col inner (A reuse)
  int col = chunk * 4 + (rr & 3);   // [0,16)
  int b = brt >> 2, rt = brt & 3;
  int g = b * 8 + e;
  int n = counts[g];
  int row0 = rt * 256;
  if (row0 >= n) return;
  int col0 = col * 128;

  // per buf (u16): Ak0[256*32] Ak1[256*32] Fk0[128*32] Fk1 Gk0 Gk1 = 32768
  __shared__ u16 LDSb[2][32768];    // 128 KB
  const int AK0 = 0, AK1 = 8192, FK0 = 16384, FK1 = 20480, GK0 = 24576, GK1 = 28672;

  int tid = threadIdx.x;
  int lane = tid & 63, wid = tid >> 6;   // 8 waves
  int wr = wid >> 1, wc = wid & 1;       // 4M x 2N, wave 64x64 dual
  int fr = lane & 15, fq = lane >> 4;
  int sw = (fq ^ (fr & 3)) * 8;          // swizzled 16B slot in 64B row (u16)
  bool active = (row0 + wr * 64) < n;    // wave-uniform tail skip

  // staging sources. A-half unit: 1024 chunks, 2 gl16/thread; F/G half: 512, 1.
  const u16* sA[2][2];    // [kk][i]
  #pragma unroll
  for (int i = 0; i < 2; ++i) {
    int cid = (i * 8 + wid) * 64 + lane;     // [0,1024)
    int row = cid >> 2, sl = cid & 3;
    int slot = row0 + row;
    int t0 = tok[g * T_ + (slot < n ? slot : n - 1)];
    const u16* base = xb + ((size_t)(b * T_ + t0)) * C_ + ((sl ^ (row & 3)) * 8);
    sA[0][i] = base;
    sA[1][i] = base + 32;
  }
  const u16* sF[2]; const u16* sG[2];
  {
    int cid = wid * 64 + lane;               // [0,512)
    int row = cid >> 2, sl = cid & 3;
    int kc = (sl ^ (row & 3)) * 8;
    const u16* bf_ = wfcT + ((size_t)e * H_ + col0 + row) * C_ + kc;
    const u16* bg_ = wgT  + ((size_t)e * H_ + col0 + row) * C_ + kc;
    sF[0] = bf_; sF[1] = bf_ + 32;
    sG[0] = bg_; sG[1] = bg_ + 32;
  }
  int dA0 = (0 * 8 + wid) * 512, dA1 = (1 * 8 + wid) * 512;  // u16 dst within unit
  int dB = wid * 512;

  f32x4 ah[4][4] = {}; f32x4 ag[4][4] = {};

  // prologue: tile 0 -> buf 0, order A0k0,A1k0,Fk0,Gk0,A0k1,A1k1,Fk1,Gk1
  {
    u16* L = &LDSb[0][0];
    gl16(sA[0][0], L + AK0 + dA0); gl16(sA[0][1], L + AK0 + dA1);
    gl16(sF[0],    L + FK0 + dB);  gl16(sG[0],    L + GK0 + dB);
    gl16(sA[1][0], L + AK1 + dA0); gl16(sA[1][1], L + AK1 + dA1);
    gl16(sF[1],    L + FK1 + dB);  gl16(sG[1],    L + GK1 + dB);
  }
  VMCNT(5);   // certify Ak0,Fk0 of tile 0
  BAR();

  for (int t = 0; t < 16; ++t) {
    int pb = t & 1;
    bool st = t < 15;
    int kt = (t + 1) * 64;
    const u16* Lc = &LDSb[pb][0];
    u16* Ln = &LDSb[pb ^ 1][0];
    bf16x8 a[4], f[4], gg[4];
    // ---- P0: reads a@kk0 + f@kk0 ; stage Ak0(t+1) ; certify Gk0(t)
    if (active) {
      #pragma unroll
      for (int m = 0; m < 4; ++m)
        a[m] = *reinterpret_cast<const bf16x8*>(&Lc[AK0 + (wr * 64 + m * 16 + fr) * 32 + sw]);
      #pragma unroll
      for (int j = 0; j < 4; ++j)
        f[j] = *reinterpret_cast<const bf16x8*>(&Lc[FK0 + (wc * 64 + j * 16 + fr) * 32 + sw]);
    }
    if (st) { gl16(sA[0][0] + kt, Ln + AK0 + dA0); gl16(sA[0][1] + kt, Ln + AK0 + dA1); }
    if (st) { VMCNT(6); } else { VMCNT(4); }
    BAR();
    if (active) {
      PRIO1();
      #pragma unroll
      for (int m = 0; m < 4; ++m)
        #pragma unroll
        for (int j = 0; j < 4; ++j)
          ah[m][j] = MFMA(a[m], f[j], ah[m][j], 0, 0, 0);
      PRIO0();
    }
    // ---- P1: reads g@kk0 ; stage Fk0,Gk0(t+1) ; certify Ak1,Fk1(t)
    if (active) {
      #pragma unroll
      for (int j = 0; j < 4; ++j)
        gg[j] = *reinterpret_cast<const bf16x8*>(&Lc[GK0 + (wc * 64 + j * 16 + fr) * 32 + sw]);
    }
    if (st) { gl16(sF[0] + kt, Ln + FK0 + dB); gl16(sG[0] + kt, Ln + GK0 + dB); }
    if (st) { VMCNT(5); } else { VMCNT(1); }
    BAR();
    if (active) {
      PRIO1();
      #pragma unroll
      for (int m = 0; m < 4; ++m)
        #pragma unroll
        for (int j = 0; j < 4; ++j)
          ag[m][j] = MFMA(a[m], gg[j], ag[m][j], 0, 0, 0);
      PRIO0();
    }
    // ---- P2: reads a@kk1 + f@kk1 ; stage Ak1(t+1) ; certify Gk1(t)
    if (active) {
      #pragma unroll
      for (int m = 0; m < 4; ++m)
        a[m] = *reinterpret_cast<const bf16x8*>(&Lc[AK1 + (wr * 64 + m * 16 + fr) * 32 + sw]);
      #pragma unroll
      for (int j = 0; j < 4; ++j)
        f[j] = *reinterpret_cast<const bf16x8*>(&Lc[FK1 + (wc * 64 + j * 16 + fr) * 32 + sw]);
    }
    if (st) { gl16(sA[1][0] + kt, Ln + AK1 + dA0); gl16(sA[1][1] + kt, Ln + AK1 + dA1); }
    if (st) { VMCNT(6); } else { VMCNT(0); }
    BAR();
    if (active) {
      PRIO1();
      #pragma unroll
      for (int m = 0; m < 4; ++m)
        #pragma unroll
        for (int j = 0; j < 4; ++j)
          ah[m][j] = MFMA(a[m], f[j], ah[m][j], 0, 0, 0);
      PRIO0();
    }
    // ---- P3: reads g@kk1 ; stage Fk1,Gk1(t+1) ; certify Ak0,Fk0(t+1)
    if (active) {
      #pragma unroll
      for (int j = 0; j < 4; ++j)
        gg[j] = *reinterpret_cast<const bf16x8*>(&Lc[GK1 + (wc * 64 + j * 16 + fr) * 32 + sw]);
    }
    if (st) { gl16(sF[1] + kt, Ln + FK1 + dB); gl16(sG[1] + kt, Ln + GK1 + dB); }
    if (st) { VMCNT(5); }
    BAR();
    if (active) {
      PRIO1();
      #pragma unroll
      for (int m = 0; m < 4; ++m)
        #pragma unroll
        for (int j = 0; j < 4; ++j)
          ag[m][j] = MFMA(a[m], gg[j], ag[m][j], 0, 0, 0);
      PRIO0();
    }
  }

  int base = offsets[g];
  #pragma unroll
  for (int m = 0; m < 4; ++m) {
    #pragma unroll
    for (int rj = 0; rj < 4; ++rj) {
      int slot = row0 + wr * 64 + m * 16 + fq * 4 + rj;
      if (slot < n) {
        size_t rowb = (size_t)(base + slot) * H_;
        #pragma unroll
        for (int j = 0; j < 4; ++j) {
          int hc = col0 + wc * 64 + j * 16 + fr;
          float h  = ah[m][j][rj] + bfc[e * H_ + hc];
          float gp = ag[m][j][rj] + bg[e * H_ + hc];
          inter[rowb + hc] = f2bf(h * gp / (1.f + expf(-gp)));   // h * silu(gp)
        }
      }
    }
  }
}

// ---------- GEMM2: obuf = inter@Wproj + bp  (non-atomic, compacted rows) ----------
// r9 version UNCHANGED (m97 structure).
__global__ __launch_bounds__(256) void k_ffn2(
    const u16* __restrict__ inter, const u16* __restrict__ wpT,
    const float* __restrict__ bp,
    const int* __restrict__ counts, const int* __restrict__ offsets,
    float* __restrict__ obuf) {
  int bid = blockIdx.x;
  int e = bid & 7;                  // XCD pin
  int r = bid >> 3;                 // [0,512)
  int chunk = r >> 7;               // [0,4)  2-coltile chunk (1MB wpT -> L2)
  int rr = r & 127;
  int brt = rr >> 1;                // [0,64) = 8b x 8rt
  int col = chunk * 2 + (rr & 1);   // [0,8)
  int b = brt >> 3, rt = brt & 7;
  int g = b * 8 + e;
  int n = counts[g];
  int row0 = rt * 128;
  if (row0 >= n) return;
  int col0 = col * 128;
  int base = offsets[g];

  __shared__ u16 As[128 * 64];      // 16 KB
  __shared__ u16 Bs[128 * 64];      // 16 KB

  int tid = threadIdx.x;
  int lane = tid & 63, wid = tid >> 6;
  int wr = wid >> 1, wc = wid & 1;       // 2M x 2N (wave 64x64)
  int fr = lane & 15, fq = lane >> 4;
  int q = fr & 7;

  const u16* sA[4]; const u16* sB[4];
  #pragma unroll
  for (int i = 0; i < 4; ++i) {
    int ck = i * 256 + tid;              // [0,1024): row=ck>>3, slot=ck&7
    int row = ck >> 3;
    int kc = ((ck & 7) ^ (row & 7)) * 8; // inverse-swizzled source slot
    int slot = row0 + row;
    int rg = base + (slot < n ? slot : n - 1);   // clamp into valid rows
    sA[i] = inter + (size_t)rg * H_ + kc;
    sB[i] = wpT + ((size_t)e * C_ + col0 + row) * H_ + kc;
  }

  f32x4 acc[4][4] = {};

  for (int kt = 0; kt < H_; kt += 64) {
    __syncthreads();                     // prior tile's reads done
    #pragma unroll
    for (int i = 0; i < 4; ++i) {
      gl16(sA[i] + kt, (u16*)As + i * 2048 + wid * 512);
      gl16(sB[i] + kt, (u16*)Bs + i * 2048 + wid * 512);
    }
    __syncthreads();                     // compiler drains vmcnt before barrier
    #pragma unroll
    for (int kk = 0; kk < 2; ++kk) {
      int so = ((kk * 4 + fq) ^ q) * 8;  // swizzled read slot
      bf16x8 a[4], bb[4];
      #pragma unroll
      for (int m = 0; m < 4; ++m)
        a[m] = *reinterpret_cast<const bf16x8*>(&As[(wr * 64 + m * 16 + fr) * 64 + so]);
      #pragma unroll
      for (int j = 0; j < 4; ++j)
        bb[j] = *reinterpret_cast<const bf16x8*>(&Bs[(wc * 64 + j * 16 + fr) * 64 + so]);
      #pragma unroll
      for (int m = 0; m < 4; ++m)
        #pragma unroll
        for (int j = 0; j < 4; ++j)
          acc[m][j] = MFMA(a[m], bb[j], acc[m][j], 0, 0, 0);
    }
  }

  #pragma unroll
  for (int m = 0; m < 4; ++m) {
    #pragma unroll
    for (int rj = 0; rj < 4; ++rj) {
      int slot = row0 + wr * 64 + m * 16 + fq * 4 + rj;
      if (slot < n) {
        float* orow = obuf + (size_t)(base + slot) * C_;
        #pragma unroll
        for (int j = 0; j < 4; ++j) {
          int cc = col0 + wc * 64 + j * 16 + fr;
          orow[cc] = acc[m][j][rj] + bp[e * C_ + cc];
        }
      }
    }
  }
}

// ---------- combine: y[t] = p0*obuf[r0] + p1*obuf[r1] ----------
__global__ __launch_bounds__(256) void k_combine(const float* __restrict__ obuf,
                                                 const int* __restrict__ offsets,
                                                 const int* __restrict__ inv,
                                                 const float* __restrict__ pw,
                                                 float* __restrict__ y) {
  int tt = blockIdx.x;
  int c = threadIdx.x * 4;
  int i0 = inv[tt * 2 + 0], i1 = inv[tt * 2 + 1];
  int r0 = offsets[i0 >> 10] + (i0 & (T_ - 1));
  int r1 = offsets[i1 >> 10] + (i1 & (T_ - 1));
  float p0 = pw[i0], p1 = pw[i1];
  float4 a = *reinterpret_cast<const float4*>(obuf + (size_t)r0 * C_ + c);
  float4 bv = *reinterpret_cast<const float4*>(obuf + (size_t)r1 * C_ + c);
  float4 o;
  o.x = p0 * a.x + p1 * bv.x;
  o.y = p0 * a.y + p1 * bv.y;
  o.z = p0 * a.z + p1 * bv.z;
  o.w = p0 * a.w + p1 * bv.w;
  *reinterpret_cast<float4*>(y + (size_t)tt * C_ + c) = o;
}

extern "C" void kernel_launch(void* const* d_in, const int* in_sizes, int n_in,
                              void* d_out, int out_size, void* d_ws, size_t ws_size,
                              hipStream_t stream) {
  const float* x   = (const float*)d_in[0];
  const float* rw  = (const float*)d_in[1];
  const float* wfc = (const float*)d_in[2];
  const float* bfc = (const float*)d_in[3];
  const float* wg  = (const float*)d_in[4];
  const float* bg  = (const float*)d_in[5];
  const float* wp  = (const float*)d_in[6];
  const float* bp  = (const float*)d_in[7];
  float* y = (float*)d_out;

  char* ws = (char*)d_ws;
  // ws layout (bytes). obuf aliases wfcT+wgT (dead after k_ffn1); total ~177MB.
  const size_t OFF_COUNTS  = 0;                        // 64 ints
  const size_t OFF_OFFSETS = 1024;                     // 65 ints
  const size_t OFF_TOK     = 2048;                     // 256 KB
  const size_t OFF_PW      = OFF_TOK + 262144;         // 256 KB
  const size_t OFF_INV     = OFF_PW + 262144;          // 128 KB
  const size_t OFF_SELE    = OFF_INV + 131072;         // 64 KB
  const size_t OFF_SELP    = OFF_SELE + 65536;         // 64 KB
  const size_t OFF_XB      = OFF_SELP + 65536;         // 16 MB bf16 x
  const size_t OFF_WPT     = OFF_XB + (size_t)B_ * T_ * C_ * 2;     // 32 MB
  const size_t OFF_INTER   = OFF_WPT + (size_t)E_ * H_ * C_ * 2;    // 64 MB bf16
  const size_t OFF_WFCT    = OFF_INTER + (size_t)NROWS * H_ * 2;    // 32 MB
  const size_t OFF_WGT     = OFF_WFCT + (size_t)E_ * C_ * H_ * 2;   // 32 MB
  const size_t OFF_OBUF    = OFF_WFCT;                 // 64 MB f32, aliases wfcT+wgT
  int*   counts  = (int*)(ws + OFF_COUNTS);
  int*   offsets = (int*)(ws + OFF_OFFSETS);
  int*   tok     = (int*)(ws + OFF_TOK);
  float* pw      = (float*)(ws + OFF_PW);
  int*   inv     = (int*)(ws + OFF_INV);
  int*   sel_e   = (int*)(ws + OFF_SELE);
  float* sel_p   = (float*)(ws + OFF_SELP);
  u16*   xb      = (u16*)(ws + OFF_XB);
  u16*   wpT     = (u16*)(ws + OFF_WPT);
  u16*   inter   = (u16*)(ws + OFF_INTER);
  u16*   wfcT    = (u16*)(ws + OFF_WFCT);
  u16*   wgT     = (u16*)(ws + OFF_WGT);
  float* obuf    = (float*)(ws + OFF_OBUF);

  k_wt<<<dim3(H_ / 64, C_ / 64, E_), 256, 0, stream>>>(wfc, wfcT, C_, H_);
  k_wt<<<dim3(H_ / 64, C_ / 64, E_), 256, 0, stream>>>(wg, wgT, C_, H_);
  k_wt<<<dim3(C_ / 64, H_ / 64, E_), 256, 0, stream>>>(wp, wpT, H_, C_);
  k_router<<<(B_ * T_) / 4, 256, 0, stream>>>(x, rw, xb, sel_e, sel_p);
  k_place<<<B_, 256, 0, stream>>>(sel_e, sel_p, counts, tok, pw, inv);
  k_prefix<<<1, 64, 0, stream>>>(counts, offsets);
  k_ffn1<<<4096, 512, 0, stream>>>(
      xb, wfcT, wgT, bfc, bg, counts, offsets, tok, inter);
  k_ffn2<<<4096, 256, 0, stream>>>(
      inter, wpT, bp, counts, offsets, obuf);
  k_combine<<<B_ * T_, 256, 0, stream>>>(obuf, offsets, inv, pw, y);
  (void)in_sizes; (void)n_in; (void)ws_size;
}

// Round 13
// 428.089 us; speedup vs baseline: 1.0527x; 1.0527x over previous
//
#include <hip/hip_runtime.h>

#define E_ 8
#define C_ 1024
#define H_ 2048
#define B_ 8
#define T_ 1024
#define NGRP 64          // B_*E_
#define NROWS 16384      // B_*T_*K

typedef __bf16 bf16x8 __attribute__((ext_vector_type(8)));
typedef float f32x4 __attribute__((ext_vector_type(4)));
typedef unsigned short u16;

__device__ __forceinline__ u16 f2bf(float f) {
  unsigned u = __float_as_uint(f);
  u += 0x7FFFu + ((u >> 16) & 1u);   // RNE; inputs finite
  return (u16)(u >> 16);
}

// async global->LDS, 16B per lane; lds dst is wave-uniform base + lane*16
__device__ __forceinline__ void gl16(const u16* g, u16* l) {
  __builtin_amdgcn_global_load_lds(
      (const __attribute__((address_space(1))) void*)g,
      (__attribute__((address_space(3))) void*)l, 16, 0, 0);
}

#define MFMA __builtin_amdgcn_mfma_f32_16x16x32_bf16
#define BAR() __builtin_amdgcn_s_barrier()
#define VMCNT(N) asm volatile("s_waitcnt vmcnt(" #N ")" ::: "memory")
#define PRIO1() __builtin_amdgcn_s_setprio(1)
#define PRIO0() __builtin_amdgcn_s_setprio(0)

// ---------- weights: all three transposes in ONE launch (single tail) ----------
// w=0: wfc [C][H] -> wfcT [H][C]; w=1: wg likewise; w=2: wp [H][C] -> wpT [C][H].
// Body identical to the r11 k_wt (64x64 tile, [64][66] pad, ushort4 writes).
__global__ __launch_bounds__(256) void k_wt3(const float* __restrict__ wfc,
                                             const float* __restrict__ wg,
                                             const float* __restrict__ wp,
                                             u16* __restrict__ wfcT,
                                             u16* __restrict__ wgT,
                                             u16* __restrict__ wpT) {
  __shared__ u16 tile[64][66];
  int bid = blockIdx.x;
  int w = bid >> 12;                // [0,3)  (4096 blocks per weight)
  int rem = bid & 4095;
  int e = rem >> 9;                 // [0,8)
  int rem2 = rem & 511;
  int R, S, sx, sy;
  const float* in;
  u16* out;
  if (w == 0)      { in = wfc; out = wfcT; R = C_; S = H_; sx = rem2 & 31; sy = rem2 >> 5; }
  else if (w == 1) { in = wg;  out = wgT;  R = C_; S = H_; sx = rem2 & 31; sy = rem2 >> 5; }
  else             { in = wp;  out = wpT;  R = H_; S = C_; sx = rem2 & 15; sy = rem2 >> 4; }
  int s0 = sx * 64, r0 = sy * 64;
  int tx = threadIdx.x & 15, ty = threadIdx.x >> 4;
  const float* src = in + ((size_t)e * R + r0) * S + s0;
  #pragma unroll
  for (int i = 0; i < 4; ++i) {
    int rr = i * 16 + ty;
    float4 v = *reinterpret_cast<const float4*>(src + (size_t)rr * S + tx * 4);
    tile[rr][tx * 4 + 0] = f2bf(v.x);
    tile[rr][tx * 4 + 1] = f2bf(v.y);
    tile[rr][tx * 4 + 2] = f2bf(v.z);
    tile[rr][tx * 4 + 3] = f2bf(v.w);
  }
  __syncthreads();
  u16* dst = out + ((size_t)e * S + s0) * R + r0;
  #pragma unroll
  for (int i = 0; i < 4; ++i) {
    int ss = i * 16 + ty;
    ushort4 o;
    o.x = tile[tx * 4 + 0][ss];
    o.y = tile[tx * 4 + 1][ss];
    o.z = tile[tx * 4 + 2][ss];
    o.w = tile[tx * 4 + 3][ss];
    *reinterpret_cast<ushort4*>(dst + (size_t)ss * R + tx * 4) = o;
  }
}

// ---------- router pass 1: wave per token; dot products + top-2; NO atomics ----------
// r11 verbatim (r12's float4 restructure regressed; reverted).
__global__ __launch_bounds__(256) void k_router(const float* __restrict__ x,
                                                const float* __restrict__ rw,
                                                u16* __restrict__ xb,
                                                int* __restrict__ sel_e,
                                                float* __restrict__ sel_p) {
  int lane = threadIdx.x & 63;
  int tt = blockIdx.x * 4 + (threadIdx.x >> 6);    // token id 0..8191
  const float* xr = x + (size_t)tt * C_;
  u16* xo = xb + (size_t)tt * C_;
  float acc[8] = {0, 0, 0, 0, 0, 0, 0, 0};
  for (int j = 0; j < 16; ++j) {
    int c = j * 64 + lane;
    float xv = xr[c];
    xo[c] = f2bf(xv);
    float4 r0 = reinterpret_cast<const float4*>(rw + c * 8)[0];
    float4 r1 = reinterpret_cast<const float4*>(rw + c * 8)[1];
    acc[0] += xv * r0.x; acc[1] += xv * r0.y; acc[2] += xv * r0.z; acc[3] += xv * r0.w;
    acc[4] += xv * r1.x; acc[5] += xv * r1.y; acc[6] += xv * r1.z; acc[7] += xv * r1.w;
  }
  #pragma unroll
  for (int e = 0; e < 8; ++e)
    #pragma unroll
    for (int off = 32; off; off >>= 1)
      acc[e] += __shfl_xor(acc[e], off);
  if (lane == 0) {
    int e0 = 0;
    #pragma unroll
    for (int e = 1; e < 8; ++e) if (acc[e] > acc[e0]) e0 = e;   // ties -> lower idx
    int e1 = -1;
    #pragma unroll
    for (int e = 0; e < 8; ++e)
      if (e != e0 && (e1 < 0 || acc[e] > acc[e1])) e1 = e;
    float l0 = acc[e0], l1 = acc[e1];
    sel_e[tt * 2 + 0] = e0;
    sel_e[tt * 2 + 1] = e1;
    sel_p[tt * 2 + 0] = 1.f / (1.f + expf(l1 - l0));
    sel_p[tt * 2 + 1] = 1.f / (1.f + expf(l0 - l1));
  }
}

// ---------- router pass 2: per-batch placement via LDS atomics ----------
__global__ __launch_bounds__(256) void k_place(const int* __restrict__ sel_e,
                                               const float* __restrict__ sel_p,
                                               int* __restrict__ counts,
                                               int* __restrict__ tok,
                                               float* __restrict__ pw,
                                               int* __restrict__ inv) {
  __shared__ int cnt[8];
  int b = blockIdx.x;
  if (threadIdx.x < 8) cnt[threadIdx.x] = 0;
  __syncthreads();
  for (int i = 0; i < 4; ++i) {
    int t = i * 256 + threadIdx.x;
    int tt = b * T_ + t;
    #pragma unroll
    for (int k = 0; k < 2; ++k) {
      int e = sel_e[tt * 2 + k];
      float p = sel_p[tt * 2 + k];
      int slot = atomicAdd(&cnt[e], 1);        // LDS atomic: fast, block-local
      int g = b * 8 + e;
      tok[g * T_ + slot] = t;
      pw[g * T_ + slot] = p;
      inv[tt * 2 + k] = g * T_ + slot;
    }
  }
  __syncthreads();
  if (threadIdx.x < 8) counts[b * 8 + threadIdx.x] = cnt[threadIdx.x];
}

// ---------- exclusive prefix over 64 counts ----------
__global__ void k_prefix(const int* __restrict__ counts, int* __restrict__ offsets) {
  if (threadIdx.x == 0) {
    int s = 0;
    for (int i = 0; i < NGRP; ++i) { offsets[i] = s; s += counts[i]; }
    offsets[NGRP] = s;
  }
}

// ---------- GEMM1: inter = (Xe@Wfc+bfc) * silu(Xe@Wg+bg), bf16 out ----------
// r7 kernel VERBATIM (session-best 234us). kk-split units, 4 phases/tile,
// counted vmcnt 6/5/6/5, setprio; known benign ~1.4e7 bank conflicts.
__global__ __launch_bounds__(512) void k_ffn1(
    const u16* __restrict__ xb, const u16* __restrict__ wfcT, const u16* __restrict__ wgT,
    const float* __restrict__ bfc, const float* __restrict__ bg,
    const int* __restrict__ counts, const int* __restrict__ offsets,
    const int* __restrict__ tok, u16* __restrict__ inter) {
  int bid = blockIdx.x;
  int e = bid & 7;                  // XCD pin
  int r = bid >> 3;                 // [0,512)
  int chunk = r >> 7;               // [0,4)  4-coltile chunk (2MB weights -> L2)
  int rr = r & 127;
  int brt = rr >> 2;                // [0,32) (b, rowtile); col inner (A reuse)
  int col = chunk * 4 + (rr & 3);   // [0,16)
  int b = brt >> 2, rt = brt & 3;
  int g = b * 8 + e;
  int n = counts[g];
  int row0 = rt * 256;
  if (row0 >= n) return;
  int col0 = col * 128;

  // per buf (u16): Ak0[256*32] Ak1[256*32] Fk0[128*32] Fk1 Gk0 Gk1 = 32768
  __shared__ u16 LDSb[2][32768];    // 128 KB
  const int AK0 = 0, AK1 = 8192, FK0 = 16384, FK1 = 20480, GK0 = 24576, GK1 = 28672;

  int tid = threadIdx.x;
  int lane = tid & 63, wid = tid >> 6;   // 8 waves
  int wr = wid >> 1, wc = wid & 1;       // 4M x 2N, wave 64x64 dual
  int fr = lane & 15, fq = lane >> 4;
  int sw = (fq ^ (fr & 3)) * 8;          // swizzled 16B slot in 64B row (u16)
  bool active = (row0 + wr * 64) < n;    // wave-uniform tail skip

  // staging sources. A-half unit: 1024 chunks, 2 gl16/thread; F/G half: 512, 1.
  const u16* sA[2][2];    // [kk][i]
  #pragma unroll
  for (int i = 0; i < 2; ++i) {
    int cid = (i * 8 + wid) * 64 + lane;     // [0,1024)
    int row = cid >> 2, sl = cid & 3;
    int slot = row0 + row;
    int t0 = tok[g * T_ + (slot < n ? slot : n - 1)];
    const u16* base = xb + ((size_t)(b * T_ + t0)) * C_ + ((sl ^ (row & 3)) * 8);
    sA[0][i] = base;
    sA[1][i] = base + 32;
  }
  const u16* sF[2]; const u16* sG[2];
  {
    int cid = wid * 64 + lane;               // [0,512)
    int row = cid >> 2, sl = cid & 3;
    int kc = (sl ^ (row & 3)) * 8;
    const u16* bf_ = wfcT + ((size_t)e * H_ + col0 + row) * C_ + kc;
    const u16* bg_ = wgT  + ((size_t)e * H_ + col0 + row) * C_ + kc;
    sF[0] = bf_; sF[1] = bf_ + 32;
    sG[0] = bg_; sG[1] = bg_ + 32;
  }
  int dA0 = (0 * 8 + wid) * 512, dA1 = (1 * 8 + wid) * 512;  // u16 dst within unit
  int dB = wid * 512;

  f32x4 ah[4][4] = {}; f32x4 ag[4][4] = {};

  // prologue: tile 0 -> buf 0, order A0k0,A1k0,Fk0,Gk0,A0k1,A1k1,Fk1,Gk1
  {
    u16* L = &LDSb[0][0];
    gl16(sA[0][0], L + AK0 + dA0); gl16(sA[0][1], L + AK0 + dA1);
    gl16(sF[0],    L + FK0 + dB);  gl16(sG[0],    L + GK0 + dB);
    gl16(sA[1][0], L + AK1 + dA0); gl16(sA[1][1], L + AK1 + dA1);
    gl16(sF[1],    L + FK1 + dB);  gl16(sG[1],    L + GK1 + dB);
  }
  VMCNT(5);   // certify Ak0,Fk0 of tile 0
  BAR();

  for (int t = 0; t < 16; ++t) {
    int pb = t & 1;
    bool st = t < 15;
    int kt = (t + 1) * 64;
    const u16* Lc = &LDSb[pb][0];
    u16* Ln = &LDSb[pb ^ 1][0];
    bf16x8 a[4], f[4], gg[4];
    // ---- P0: reads a@kk0 + f@kk0 ; stage Ak0(t+1) ; certify Gk0(t)
    if (active) {
      #pragma unroll
      for (int m = 0; m < 4; ++m)
        a[m] = *reinterpret_cast<const bf16x8*>(&Lc[AK0 + (wr * 64 + m * 16 + fr) * 32 + sw]);
      #pragma unroll
      for (int j = 0; j < 4; ++j)
        f[j] = *reinterpret_cast<const bf16x8*>(&Lc[FK0 + (wc * 64 + j * 16 + fr) * 32 + sw]);
    }
    if (st) { gl16(sA[0][0] + kt, Ln + AK0 + dA0); gl16(sA[0][1] + kt, Ln + AK0 + dA1); }
    if (st) { VMCNT(6); } else { VMCNT(4); }
    BAR();
    if (active) {
      PRIO1();
      #pragma unroll
      for (int m = 0; m < 4; ++m)
        #pragma unroll
        for (int j = 0; j < 4; ++j)
          ah[m][j] = MFMA(a[m], f[j], ah[m][j], 0, 0, 0);
      PRIO0();
    }
    // ---- P1: reads g@kk0 ; stage Fk0,Gk0(t+1) ; certify Ak1,Fk1(t)
    if (active) {
      #pragma unroll
      for (int j = 0; j < 4; ++j)
        gg[j] = *reinterpret_cast<const bf16x8*>(&Lc[GK0 + (wc * 64 + j * 16 + fr) * 32 + sw]);
    }
    if (st) { gl16(sF[0] + kt, Ln + FK0 + dB); gl16(sG[0] + kt, Ln + GK0 + dB); }
    if (st) { VMCNT(5); } else { VMCNT(1); }
    BAR();
    if (active) {
      PRIO1();
      #pragma unroll
      for (int m = 0; m < 4; ++m)
        #pragma unroll
        for (int j = 0; j < 4; ++j)
          ag[m][j] = MFMA(a[m], gg[j], ag[m][j], 0, 0, 0);
      PRIO0();
    }
    // ---- P2: reads a@kk1 + f@kk1 ; stage Ak1(t+1) ; certify Gk1(t)
    if (active) {
      #pragma unroll
      for (int m = 0; m < 4; ++m)
        a[m] = *reinterpret_cast<const bf16x8*>(&Lc[AK1 + (wr * 64 + m * 16 + fr) * 32 + sw]);
      #pragma unroll
      for (int j = 0; j < 4; ++j)
        f[j] = *reinterpret_cast<const bf16x8*>(&Lc[FK1 + (wc * 64 + j * 16 + fr) * 32 + sw]);
    }
    if (st) { gl16(sA[1][0] + kt, Ln + AK1 + dA0); gl16(sA[1][1] + kt, Ln + AK1 + dA1); }
    if (st) { VMCNT(6); } else { VMCNT(0); }
    BAR();
    if (active) {
      PRIO1();
      #pragma unroll
      for (int m = 0; m < 4; ++m)
        #pragma unroll
        for (int j = 0; j < 4; ++j)
          ah[m][j] = MFMA(a[m], f[j], ah[m][j], 0, 0, 0);
      PRIO0();
    }
    // ---- P3: reads g@kk1 ; stage Fk1,Gk1(t+1) ; certify Ak0,Fk0(t+1)
    if (active) {
      #pragma unroll
      for (int j = 0; j < 4; ++j)
        gg[j] = *reinterpret_cast<const bf16x8*>(&Lc[GK1 + (wc * 64 + j * 16 + fr) * 32 + sw]);
    }
    if (st) { gl16(sF[1] + kt, Ln + FK1 + dB); gl16(sG[1] + kt, Ln + GK1 + dB); }
    if (st) { VMCNT(5); }
    BAR();
    if (active) {
      PRIO1();
      #pragma unroll
      for (int m = 0; m < 4; ++m)
        #pragma unroll
        for (int j = 0; j < 4; ++j)
          ag[m][j] = MFMA(a[m], gg[j], ag[m][j], 0, 0, 0);
      PRIO0();
    }
  }

  int base = offsets[g];
  #pragma unroll
  for (int m = 0; m < 4; ++m) {
    #pragma unroll
    for (int rj = 0; rj < 4; ++rj) {
      int slot = row0 + wr * 64 + m * 16 + fq * 4 + rj;
      if (slot < n) {
        size_t rowb = (size_t)(base + slot) * H_;
        #pragma unroll
        for (int j = 0; j < 4; ++j) {
          int hc = col0 + wc * 64 + j * 16 + fr;
          float h  = ah[m][j][rj] + bfc[e * H_ + hc];
          float gp = ag[m][j][rj] + bg[e * H_ + hc];
          inter[rowb + hc] = f2bf(h * gp / (1.f + expf(-gp)));   // h * silu(gp)
        }
      }
    }
  }
}

// ---------- GEMM2: obuf = inter@Wproj + bp  (non-atomic, compacted rows) ----------
// r9 version UNCHANGED (m97 structure).
__global__ __launch_bounds__(256) void k_ffn2(
    const u16* __restrict__ inter, const u16* __restrict__ wpT,
    const float* __restrict__ bp,
    const int* __restrict__ counts, const int* __restrict__ offsets,
    float* __restrict__ obuf) {
  int bid = blockIdx.x;
  int e = bid & 7;                  // XCD pin
  int r = bid >> 3;                 // [0,512)
  int chunk = r >> 7;               // [0,4)  2-coltile chunk (1MB wpT -> L2)
  int rr = r & 127;
  int brt = rr >> 1;                // [0,64) = 8b x 8rt
  int col = chunk * 2 + (rr & 1);   // [0,8)
  int b = brt >> 3, rt = brt & 7;
  int g = b * 8 + e;
  int n = counts[g];
  int row0 = rt * 128;
  if (row0 >= n) return;
  int col0 = col * 128;
  int base = offsets[g];

  __shared__ u16 As[128 * 64];      // 16 KB
  __shared__ u16 Bs[128 * 64];      // 16 KB

  int tid = threadIdx.x;
  int lane = tid & 63, wid = tid >> 6;
  int wr = wid >> 1, wc = wid & 1;       // 2M x 2N (wave 64x64)
  int fr = lane & 15, fq = lane >> 4;
  int q = fr & 7;

  const u16* sA[4]; const u16* sB[4];
  #pragma unroll
  for (int i = 0; i < 4; ++i) {
    int ck = i * 256 + tid;              // [0,1024): row=ck>>3, slot=ck&7
    int row = ck >> 3;
    int kc = ((ck & 7) ^ (row & 7)) * 8; // inverse-swizzled source slot
    int slot = row0 + row;
    int rg = base + (slot < n ? slot : n - 1);   // clamp into valid rows
    sA[i] = inter + (size_t)rg * H_ + kc;
    sB[i] = wpT + ((size_t)e * C_ + col0 + row) * H_ + kc;
  }

  f32x4 acc[4][4] = {};

  for (int kt = 0; kt < H_; kt += 64) {
    __syncthreads();                     // prior tile's reads done
    #pragma unroll
    for (int i = 0; i < 4; ++i) {
      gl16(sA[i] + kt, (u16*)As + i * 2048 + wid * 512);
      gl16(sB[i] + kt, (u16*)Bs + i * 2048 + wid * 512);
    }
    __syncthreads();                     // compiler drains vmcnt before barrier
    #pragma unroll
    for (int kk = 0; kk < 2; ++kk) {
      int so = ((kk * 4 + fq) ^ q) * 8;  // swizzled read slot
      bf16x8 a[4], bb[4];
      #pragma unroll
      for (int m = 0; m < 4; ++m)
        a[m] = *reinterpret_cast<const bf16x8*>(&As[(wr * 64 + m * 16 + fr) * 64 + so]);
      #pragma unroll
      for (int j = 0; j < 4; ++j)
        bb[j] = *reinterpret_cast<const bf16x8*>(&Bs[(wc * 64 + j * 16 + fr) * 64 + so]);
      #pragma unroll
      for (int m = 0; m < 4; ++m)
        #pragma unroll
        for (int j = 0; j < 4; ++j)
          acc[m][j] = MFMA(a[m], bb[j], acc[m][j], 0, 0, 0);
    }
  }

  #pragma unroll
  for (int m = 0; m < 4; ++m) {
    #pragma unroll
    for (int rj = 0; rj < 4; ++rj) {
      int slot = row0 + wr * 64 + m * 16 + fq * 4 + rj;
      if (slot < n) {
        float* orow = obuf + (size_t)(base + slot) * C_;
        #pragma unroll
        for (int j = 0; j < 4; ++j) {
          int cc = col0 + wc * 64 + j * 16 + fr;
          orow[cc] = acc[m][j][rj] + bp[e * C_ + cc];
        }
      }
    }
  }
}

// ---------- combine: y[t] = p0*obuf[r0] + p1*obuf[r1] ----------
__global__ __launch_bounds__(256) void k_combine(const float* __restrict__ obuf,
                                                 const int* __restrict__ offsets,
                                                 const int* __restrict__ inv,
                                                 const float* __restrict__ pw,
                                                 float* __restrict__ y) {
  int tt = blockIdx.x;
  int c = threadIdx.x * 4;
  int i0 = inv[tt * 2 + 0], i1 = inv[tt * 2 + 1];
  int r0 = offsets[i0 >> 10] + (i0 & (T_ - 1));
  int r1 = offsets[i1 >> 10] + (i1 & (T_ - 1));
  float p0 = pw[i0], p1 = pw[i1];
  float4 a = *reinterpret_cast<const float4*>(obuf + (size_t)r0 * C_ + c);
  float4 bv = *reinterpret_cast<const float4*>(obuf + (size_t)r1 * C_ + c);
  float4 o;
  o.x = p0 * a.x + p1 * bv.x;
  o.y = p0 * a.y + p1 * bv.y;
  o.z = p0 * a.z + p1 * bv.z;
  o.w = p0 * a.w + p1 * bv.w;
  *reinterpret_cast<float4*>(y + (size_t)tt * C_ + c) = o;
}

extern "C" void kernel_launch(void* const* d_in, const int* in_sizes, int n_in,
                              void* d_out, int out_size, void* d_ws, size_t ws_size,
                              hipStream_t stream) {
  const float* x   = (const float*)d_in[0];
  const float* rw  = (const float*)d_in[1];
  const float* wfc = (const float*)d_in[2];
  const float* bfc = (const float*)d_in[3];
  const float* wg  = (const float*)d_in[4];
  const float* bg  = (const float*)d_in[5];
  const float* wp  = (const float*)d_in[6];
  const float* bp  = (const float*)d_in[7];
  float* y = (float*)d_out;

  char* ws = (char*)d_ws;
  // ws layout (bytes). obuf aliases wfcT+wgT (dead after k_ffn1); total ~177MB.
  const size_t OFF_COUNTS  = 0;                        // 64 ints
  const size_t OFF_OFFSETS = 1024;                     // 65 ints
  const size_t OFF_TOK     = 2048;                     // 256 KB
  const size_t OFF_PW      = OFF_TOK + 262144;         // 256 KB
  const size_t OFF_INV     = OFF_PW + 262144;          // 128 KB
  const size_t OFF_SELE    = OFF_INV + 131072;         // 64 KB
  const size_t OFF_SELP    = OFF_SELE + 65536;         // 64 KB
  const size_t OFF_XB      = OFF_SELP + 65536;         // 16 MB bf16 x
  const size_t OFF_WPT     = OFF_XB + (size_t)B_ * T_ * C_ * 2;     // 32 MB
  const size_t OFF_INTER   = OFF_WPT + (size_t)E_ * H_ * C_ * 2;    // 64 MB bf16
  const size_t OFF_WFCT    = OFF_INTER + (size_t)NROWS * H_ * 2;    // 32 MB
  const size_t OFF_WGT     = OFF_WFCT + (size_t)E_ * C_ * H_ * 2;   // 32 MB
  const size_t OFF_OBUF    = OFF_WFCT;                 // 64 MB f32, aliases wfcT+wgT
  int*   counts  = (int*)(ws + OFF_COUNTS);
  int*   offsets = (int*)(ws + OFF_OFFSETS);
  int*   tok     = (int*)(ws + OFF_TOK);
  float* pw      = (float*)(ws + OFF_PW);
  int*   inv     = (int*)(ws + OFF_INV);
  int*   sel_e   = (int*)(ws + OFF_SELE);
  float* sel_p   = (float*)(ws + OFF_SELP);
  u16*   xb      = (u16*)(ws + OFF_XB);
  u16*   wpT     = (u16*)(ws + OFF_WPT);
  u16*   inter   = (u16*)(ws + OFF_INTER);
  u16*   wfcT    = (u16*)(ws + OFF_WFCT);
  u16*   wgT     = (u16*)(ws + OFF_WGT);
  float* obuf    = (float*)(ws + OFF_OBUF);

  k_wt3<<<3 * 4096, 256, 0, stream>>>(wfc, wg, wp, wfcT, wgT, wpT);
  k_router<<<(B_ * T_) / 4, 256, 0, stream>>>(x, rw, xb, sel_e, sel_p);
  k_place<<<B_, 256, 0, stream>>>(sel_e, sel_p, counts, tok, pw, inv);
  k_prefix<<<1, 64, 0, stream>>>(counts, offsets);
  k_ffn1<<<4096, 512, 0, stream>>>(
      xb, wfcT, wgT, bfc, bg, counts, offsets, tok, inter);
  k_ffn2<<<4096, 256, 0, stream>>>(
      inter, wpT, bp, counts, offsets, obuf);
  k_combine<<<B_ * T_, 256, 0, stream>>>(obuf, offsets, inv, pw, y);
  (void)in_sizes; (void)n_in; (void)ws_size;
}